// Round 13
// baseline (481.401 us; speedup 1.0000x reference)
//
#include <hip/hip_runtime.h>

// LightGCN propagation on MI355X (gfx950).
//   h_{k+1}[r,:] = sum_{e: row[e]==r} val[e] * h_k[col[e],:]   D=32
//   out = (x + h1 + h2 + h3) / 4
//
// Round 13: R11/R12 accounting shows ~85-95 us of the 219.5-us best is
// inter-node launch overhead (~10 us/node x 9 nodes; kernel time is only
// ~130 us, scatter <=43). R12's node cut was polluted by a simultaneous
// record-format change (+decode VALU) -- reverted. This round: ONE change
// class. Fuse the whole build (memset-self-init + hist + cvt + scan +
// scatter + sort) into a single 391-block x 1024-thr kernel with
// ticket/flag barriers; keep R9's proven spmm launches byte-identical.
//   - co-residency by construction: __launch_bounds__(1024,8) -> VGPR<=64
//     -> 2 blocks/CU -> 512 slots >= 391 blocks (no deadlock).
//   - flags need no init: ws poison 0xAA != MAGIC; block 0 zeroes tickets
//     + bucket_tot then releases flag0 (kills the memset node).
// Nodes: 9 -> 4.

#define NN 100000
#define NE 1600000
#define DD 32
#define CHUNK 4096
#define NCHUNK ((NE + CHUNK - 1) / CHUNK)   // 391
#define BROWS 128
#define NBKT ((NN + BROWS - 1) / BROWS)     // 782
#define MAGIC 0x5C0FFEE1

__device__ __forceinline__ unsigned f2bf(float f) {
    unsigned u = __float_as_uint(f);
    return (u + 0x7fffu + ((u >> 16) & 1u)) >> 16;   // RNE
}

// ---- fused build: hist + cvt + scan + multisplit scatter + bucket sort ---

__global__ __launch_bounds__(1024, 8) void build_kernel(
    const int* __restrict__ row, const int* __restrict__ col,
    const float* __restrict__ val, const float2* __restrict__ x2,
    int* flags, int* tickets,
    int* bucket_tot, int* bucketbase, int* cursor, int* row_ptr,
    int2* tmp, int2* edges, unsigned* hb0)
{
    __shared__ int cnt[NBKT];
    __shared__ int aux[NBKT];       // gofs (scatter) / cur (sort)
    __shared__ int wt[17];
    __shared__ int s_t;
    const int tid = threadIdx.x;
    const int blk = blockIdx.x;
    const int start = blk * CHUNK;
    const int n = min(CHUNK, NE - start);

    // ---- init handshake: block 0 zeroes counters, releases flag0 --------
    if (blk == 0) {
        for (int k = tid; k < NBKT; k += 1024) bucket_tot[k] = 0;
        if (tid < 2) tickets[tid] = 0;
        __syncthreads();
        if (tid == 0) {
            __threadfence();
            __hip_atomic_store(&flags[0], MAGIC, __ATOMIC_RELEASE,
                               __HIP_MEMORY_SCOPE_AGENT);
        }
    } else {
        if (tid == 0) {
            while (__hip_atomic_load(&flags[0], __ATOMIC_ACQUIRE,
                                     __HIP_MEMORY_SCOPE_AGENT) != MAGIC)
                __builtin_amdgcn_s_sleep(1);
        }
        __syncthreads();
    }

    // ---- phase 1: chunk histogram + x -> bf16 cvt ------------------------
    for (int k = tid; k < NBKT; k += 1024) cnt[k] = 0;
    __syncthreads();
    #pragma unroll
    for (int k = 0; k < CHUNK / 1024; k++) {
        int j = k * 1024 + tid;
        if (j < n) atomicAdd(&cnt[row[start + j] >> 7], 1);
    }
    for (int j = blk * 1024 + tid; j < NN * DD / 2; j += NCHUNK * 1024) {
        float2 f = x2[j];
        hb0[j] = f2bf(f.x) | (f2bf(f.y) << 16);
    }
    __syncthreads();
    for (int k = tid; k < NBKT; k += 1024)
        if (cnt[k]) atomicAdd(&bucket_tot[k], cnt[k]);

    // ---- barrier A: last-ticket block runs the bucket scan ---------------
    __syncthreads();
    if (tid == 0) {
        __threadfence();
        s_t = __hip_atomic_fetch_add(&tickets[0], 1, __ATOMIC_ACQ_REL,
                                     __HIP_MEMORY_SCOPE_AGENT);
    }
    __syncthreads();
    if (s_t == NCHUNK - 1) {                     // block-uniform (shared s_t)
        __threadfence();
        int v = (tid < NBKT) ? bucket_tot[tid] : 0;
        int lane = tid & 63, w = tid >> 6;       // 16 waves
        int xs = v;
        #pragma unroll
        for (int off = 1; off < 64; off <<= 1) {
            int y = __shfl_up(xs, off, 64);
            if (lane >= off) xs += y;
        }
        if (lane == 63) wt[w] = xs;
        __syncthreads();
        if (w == 0 && lane < 16) {
            int y = wt[lane];
            #pragma unroll
            for (int off = 1; off < 16; off <<= 1) {
                int z = __shfl_up(y, off, 16);
                if ((lane & 15) >= off) y += z;
            }
            wt[lane] = y;                        // inclusive wave totals
        }
        __syncthreads();
        int wo = (w > 0) ? wt[w - 1] : 0;
        int excl = xs + wo - v;
        if (tid < NBKT) { bucketbase[tid] = excl; cursor[tid] = excl; }
        if (tid == NBKT) { bucketbase[NBKT] = NE; row_ptr[NN] = NE; }
        __syncthreads();
        if (tid == 0) {
            __threadfence();
            __hip_atomic_store(&flags[1], MAGIC, __ATOMIC_RELEASE,
                               __HIP_MEMORY_SCOPE_AGENT);
        }
    }
    if (tid == 0) {
        while (__hip_atomic_load(&flags[1], __ATOMIC_ACQUIRE,
                                 __HIP_MEMORY_SCOPE_AGENT) != MAGIC)
            __builtin_amdgcn_s_sleep(1);
        __threadfence();
    }
    __syncthreads();

    // ---- phase 2: multisplit scatter into bucket-contiguous tmp ----------
    for (int k = tid; k < NBKT; k += 1024) cnt[k] = 0;
    __syncthreads();
    int rrow[CHUNK / 1024], rank[CHUNK / 1024];
    #pragma unroll
    for (int k = 0; k < CHUNK / 1024; k++) {
        int j = k * 1024 + tid;
        int r = (j < n) ? row[start + j] : -1;
        rrow[k] = r;
        rank[k] = (r >= 0) ? atomicAdd(&cnt[r >> 7], 1) : 0;
    }
    __syncthreads();
    for (int k = tid; k < NBKT; k += 1024)
        if (cnt[k]) aux[k] = atomicAdd(&cursor[k], cnt[k]);
    __syncthreads();
    #pragma unroll
    for (int k = 0; k < CHUNK / 1024; k++) {
        int j = k * 1024 + tid;
        int r = rrow[k];
        if (r >= 0) {
            tmp[aux[r >> 7] + rank[k]] =
                make_int2(((r & 127) << 17) | col[start + j],
                          __float_as_int(val[start + j]));
        }
    }

    // ---- barrier B: all scatter writes globally visible ------------------
    __syncthreads();
    if (tid == 0) {
        __threadfence();
        s_t = __hip_atomic_fetch_add(&tickets[1], 1, __ATOMIC_ACQ_REL,
                                     __HIP_MEMORY_SCOPE_AGENT);
    }
    __syncthreads();
    if (s_t == NCHUNK - 1 && tid == 0) {
        __hip_atomic_store(&flags[2], MAGIC, __ATOMIC_RELEASE,
                           __HIP_MEMORY_SCOPE_AGENT);
    }
    if (tid == 0) {
        while (__hip_atomic_load(&flags[2], __ATOMIC_ACQUIRE,
                                 __HIP_MEMORY_SCOPE_AGENT) != MAGIC)
            __builtin_amdgcn_s_sleep(1);
        __threadfence();
    }
    __syncthreads();

    // ---- phase 3: row-sort buckets 2*blk and 2*blk+1 ---------------------
    #pragma unroll
    for (int q = 0; q < 2; q++) {
        const int b = 2 * blk + q;               // 391*2 = 782 = NBKT exactly
        const int s = bucketbase[b];
        const int e = bucketbase[b + 1];
        if (tid < BROWS) cnt[tid] = 0;
        __syncthreads();
        int2 rc[2];
        #pragma unroll
        for (int k = 0; k < 2; k++) {
            int j = s + k * 1024 + tid;
            rc[k] = (j < e) ? tmp[j] : make_int2(-1, 0);
            if (rc[k].x >= 0) atomicAdd(&cnt[rc[k].x >> 17], 1);
        }
        for (int j = s + 2048 + tid; j < e; j += 1024)     // overflow (rare)
            atomicAdd(&cnt[tmp[j].x >> 17], 1);
        __syncthreads();
        int v = 0, xs = 0;
        if (tid < BROWS) {
            v = cnt[tid];
            int lane = tid & 63;
            xs = v;
            #pragma unroll
            for (int off = 1; off < 64; off <<= 1) {
                int y = __shfl_up(xs, off, 64);
                if (lane >= off) xs += y;
            }
            if (lane == 63) wt[tid >> 6] = xs;
        }
        __syncthreads();
        if (tid < BROWS) {
            int excl = xs + ((tid >> 6) ? wt[0] : 0) - v;
            aux[tid] = excl;
            int r = b * BROWS + tid;
            if (r < NN) row_ptr[r] = s + excl;
        }
        __syncthreads();
        #pragma unroll
        for (int k = 0; k < 2; k++) {
            if (rc[k].x >= 0) {
                int pos = s + atomicAdd(&aux[rc[k].x >> 17], 1);
                edges[pos] = make_int2(rc[k].x & 0x1FFFF, rc[k].y);
            }
        }
        for (int j = s + 2048 + tid; j < e; j += 1024) {   // overflow (rare)
            int2 rec = tmp[j];
            int pos = s + atomicAdd(&aux[rec.x >> 17], 1);
            edges[pos] = make_int2(rec.x & 0x1FFFF, rec.y);
        }
        __syncthreads();
    }
}

// ---- SpMM (R9 exact): 4-lane group/row, bf16 uint4 gather, int2 records --
// MODE 0: houtb = bf16(A x) ; out  = x + A x
// MODE 1: houtb = bf16(A h) ; out += A h
// MODE 2: out = (out + A h) * 0.25

template <int MODE>
__global__ __launch_bounds__(256) void spmm_kernel(
    const int* __restrict__ row_ptr, const int2* __restrict__ edges,
    const uint4* __restrict__ hb4, uint4* __restrict__ houtb4,
    const float4* __restrict__ xin4, float4* __restrict__ out4)
{
    const int g = blockIdx.x * 64 + (threadIdx.x >> 2);   // row
    if (g >= NN) return;
    const int t = threadIdx.x & 3;
    const int s = row_ptr[g];
    const int e = row_ptr[g + 1];

    float acc[8] = {0.f, 0.f, 0.f, 0.f, 0.f, 0.f, 0.f, 0.f};

#define ACC8(W, V)                                                         \
    do {                                                                   \
        acc[0] += (V) * __uint_as_float((W).x << 16);                      \
        acc[1] += (V) * __uint_as_float((W).x & 0xffff0000u);              \
        acc[2] += (V) * __uint_as_float((W).y << 16);                      \
        acc[3] += (V) * __uint_as_float((W).y & 0xffff0000u);              \
        acc[4] += (V) * __uint_as_float((W).z << 16);                      \
        acc[5] += (V) * __uint_as_float((W).z & 0xffff0000u);              \
        acc[6] += (V) * __uint_as_float((W).w << 16);                      \
        acc[7] += (V) * __uint_as_float((W).w & 0xffff0000u);              \
    } while (0)

    int i = s;
    for (; i + 4 <= e; i += 4) {                 // 4 gathers in flight
        int2 a0 = edges[i];
        int2 a1 = edges[i + 1];
        int2 a2 = edges[i + 2];
        int2 a3 = edges[i + 3];
        uint4 w0 = hb4[a0.x * 4 + t];
        uint4 w1 = hb4[a1.x * 4 + t];
        uint4 w2 = hb4[a2.x * 4 + t];
        uint4 w3 = hb4[a3.x * 4 + t];
        float v0 = __int_as_float(a0.y), v1 = __int_as_float(a1.y);
        float v2 = __int_as_float(a2.y), v3 = __int_as_float(a3.y);
        ACC8(w0, v0); ACC8(w1, v1); ACC8(w2, v2); ACC8(w3, v3);
    }
    for (; i < e; ++i) {
        int2 a0 = edges[i];
        uint4 w0 = hb4[a0.x * 4 + t];
        float v0 = __int_as_float(a0.y);
        ACC8(w0, v0);
    }
#undef ACC8

    if (MODE == 0 || MODE == 1) {
        uint4 p;
        p.x = f2bf(acc[0]) | (f2bf(acc[1]) << 16);
        p.y = f2bf(acc[2]) | (f2bf(acc[3]) << 16);
        p.z = f2bf(acc[4]) | (f2bf(acc[5]) << 16);
        p.w = f2bf(acc[6]) | (f2bf(acc[7]) << 16);
        houtb4[g * 4 + t] = p;
    }
    const int o = g * 8 + t * 2;                 // two float4s per lane
    float4 lo, hi;
    if (MODE == 0) {
        float4 x0 = xin4[o], x1 = xin4[o + 1];
        lo = make_float4(x0.x + acc[0], x0.y + acc[1], x0.z + acc[2], x0.w + acc[3]);
        hi = make_float4(x1.x + acc[4], x1.y + acc[5], x1.z + acc[6], x1.w + acc[7]);
    } else if (MODE == 1) {
        float4 o0 = out4[o], o1 = out4[o + 1];
        lo = make_float4(o0.x + acc[0], o0.y + acc[1], o0.z + acc[2], o0.w + acc[3]);
        hi = make_float4(o1.x + acc[4], o1.y + acc[5], o1.z + acc[6], o1.w + acc[7]);
    } else {
        float4 o0 = out4[o], o1 = out4[o + 1];
        lo = make_float4((o0.x + acc[0]) * 0.25f, (o0.y + acc[1]) * 0.25f,
                         (o0.z + acc[2]) * 0.25f, (o0.w + acc[3]) * 0.25f);
        hi = make_float4((o1.x + acc[4]) * 0.25f, (o1.y + acc[5]) * 0.25f,
                         (o1.z + acc[6]) * 0.25f, (o1.w + acc[7]) * 0.25f);
    }
    out4[o] = lo;
    out4[o + 1] = hi;
}

// ---- launch ---------------------------------------------------------------

extern "C" void kernel_launch(void* const* d_in, const int* in_sizes, int n_in,
                              void* d_out, int out_size, void* d_ws, size_t ws_size,
                              hipStream_t stream) {
    const int*   edge_row = (const int*)d_in[0];
    const int*   edge_col = (const int*)d_in[1];
    const float* edge_val = (const float*)d_in[2];
    const float* x        = (const float*)d_in[3];
    float* out = (float*)d_out;

    char* ws = (char*)d_ws;
    int*  flags      = (int*)ws;                          // 3 (poison-init OK)
    int*  tickets    = flags + 4;                         // 2 (zeroed by blk 0)
    int*  bucket_tot = tickets + 4;                       // 782 (zeroed by blk 0)
    ws += ((size_t)(8 + NBKT) * 4 + 511) & ~511ull;
    int*  bucketbase = (int*)ws;                          ws += ((size_t)(NBKT + 1) * 4 + 511) & ~511ull;
    int*  cursor     = (int*)ws;                          ws += ((size_t)NBKT * 4 + 511) & ~511ull;
    int*  row_ptr    = (int*)ws;                          ws += ((size_t)(NN + 1) * 4 + 511) & ~511ull;
    int2* tmp        = (int2*)ws;                         ws += (size_t)NE * 8 + 64;  // 12.8 MB
    int2* edges      = (int2*)ws;                         ws += (size_t)NE * 8 + 64;  // 12.8 MB
    unsigned* hb0    = (unsigned*)ws;                     ws += (size_t)NN * DD * 2;  // 6.4 MB
    unsigned* hb1    = (unsigned*)ws;                     ws += (size_t)NN * DD * 2;  // 6.4 MB

    build_kernel<<<NCHUNK, 1024, 0, stream>>>(
        edge_row, edge_col, edge_val, (const float2*)x,
        flags, tickets, bucket_tot, bucketbase, cursor, row_ptr,
        tmp, edges, hb0);

    dim3 sp_grid((NN + 63) / 64);   // 1563 blocks, 4 lanes/row, 64 rows/block
    spmm_kernel<0><<<sp_grid, 256, 0, stream>>>(row_ptr, edges,
        (const uint4*)hb0, (uint4*)hb1, (const float4*)x, (float4*)out);
    spmm_kernel<1><<<sp_grid, 256, 0, stream>>>(row_ptr, edges,
        (const uint4*)hb1, (uint4*)hb0, (const float4*)x, (float4*)out);
    spmm_kernel<2><<<sp_grid, 256, 0, stream>>>(row_ptr, edges,
        (const uint4*)hb0, (uint4*)hb1, (const float4*)x, (float4*)out);
}